// Round 8
// baseline (164.767 us; speedup 1.0000x reference)
//
#include <hip/hip_runtime.h>
#include <stdint.h>

// Dims fixed by reference: x [T=4,B=32,C=196,N=768] fp32; w1,w2,w3 [768][768] fp32.
#define T_STEPS 4
#define BC      6272            // B*C
#define NDIM    768
#define TBC     (T_STEPS*BC)    // 25088
#define BCN     (BC*NDIM)
#define FIX_CAP 65536

typedef unsigned short u16;
typedef __attribute__((ext_vector_type(8))) __bf16 bf16x8;
typedef __attribute__((ext_vector_type(4))) float f32x4;
typedef __attribute__((ext_vector_type(4))) int   i32x4;

#define MFMA16(a,b,c)  __builtin_amdgcn_mfma_f32_16x16x32_bf16((a),(b),(c),0,0,0)
#define MFMAI8(a,b,c)  __builtin_amdgcn_mfma_i32_16x16x64_i8((a),(b),(c),0,0,0)

__device__ __forceinline__ u16 f2b(float f) {           // fp32 -> bf16 bits, RNE
    uint32_t u = __builtin_bit_cast(uint32_t, f);
    u += 0x7FFFu + ((u >> 16) & 1u);
    return (u16)(u >> 16);
}
__device__ __forceinline__ void gload16(const void* g, void* l) {
    __builtin_amdgcn_global_load_lds((const __attribute__((address_space(1))) void*)g,
                                     (__attribute__((address_space(3))) void*)l,
                                     16, 0, 0);
}

// ---------------------------------------------------------------------------
// Fused front-end: blocks [0,1568) run lif(x)+counts; blocks [1568,3872) run
// weight prep (w1->i8 x512; w2-> two i8 limbs of round(w2*65536); w3->bf16).
// ---------------------------------------------------------------------------
__global__ __launch_bounds__(256) void front_kernel(
    const float* __restrict__ x,
    const float* __restrict__ w1, const float* __restrict__ w2,
    const float* __restrict__ w3,
    int8_t* __restrict__ s8, u16* __restrict__ cnt,
    int8_t* __restrict__ w1q, int8_t* __restrict__ w2h,
    int8_t* __restrict__ w2l, u16* __restrict__ w3b,
    uint32_t* __restrict__ fix_cnt)
{
    if (blockIdx.x < BC / 4) {
        // ---- LIF over x (fp64) + per-(t,bc) spike counts ----
        const int bc   = blockIdx.x * 4 + (threadIdx.x >> 6);
        const int lane = threadIdx.x & 63;
        const size_t base = (size_t)bc * NDIM + lane * 12;

        double v[12];
        #pragma unroll
        for (int j = 0; j < 12; ++j) v[j] = 0.0;
        uint32_t c01 = 0, c23 = 0;

        #pragma unroll
        for (int t = 0; t < T_STEPS; ++t) {
            float4 xa = *(const float4*)&x[(size_t)t * BCN + base + 0];
            float4 xb = *(const float4*)&x[(size_t)t * BCN + base + 4];
            float4 xc = *(const float4*)&x[(size_t)t * BCN + base + 8];
            float xs[12] = {xa.x, xa.y, xa.z, xa.w, xb.x, xb.y, xb.z, xb.w,
                            xc.x, xc.y, xc.z, xc.w};
            uint32_t pk[3] = {0, 0, 0};
            uint32_t csum = 0;
            #pragma unroll
            for (int j = 0; j < 12; ++j) {
                v[j] = 0.5 * v[j] + (double)xs[j];
                if (v[j] >= 1.0) {
                    pk[j >> 2] |= 1u << ((j & 3) * 8);
                    csum++;
                    v[j] = 0.0;
                }
            }
            uint32_t* dst = (uint32_t*)&s8[(size_t)t * BCN + base];
            dst[0] = pk[0]; dst[1] = pk[1]; dst[2] = pk[2];
            if (t < 2) c01 += csum << (t * 16);
            else       c23 += csum << ((t - 2) * 16);
        }
        #pragma unroll
        for (int o = 32; o > 0; o >>= 1) {
            c01 += __shfl_xor(c01, o);
            c23 += __shfl_xor(c23, o);
        }
        if (lane == 0) {
            cnt[0 * BC + bc] = (u16)(c01 & 0xFFFF);
            cnt[1 * BC + bc] = (u16)(c01 >> 16);
            cnt[2 * BC + bc] = (u16)(c23 & 0xFFFF);
            cnt[3 * BC + bc] = (u16)(c23 >> 16);
        }
    } else {
        // ---- weight prep ----
        int i = (blockIdx.x - BC / 4) * 256 + threadIdx.x;  // [0, 768*768)
        if (i == 0) *fix_cnt = 0;
        int q1 = __float2int_rn(w1[i] * 512.0f);
        q1 = q1 > 127 ? 127 : (q1 < -127 ? -127 : q1);
        w1q[i] = (int8_t)q1;
        int q16 = __double2int_rn((double)w2[i] * 65536.0);
        int8_t lo = (int8_t)(q16 & 0xFF);
        int hi = (q16 - (int)lo) >> 8;                      // exact split
        w2h[i] = (int8_t)hi;
        w2l[i] = lo;
        w3b[i] = f2b(w3[i]);
    }
}

// ---------------------------------------------------------------------------
// Kernel B (i8): y1 = s@w1q^T, y2 = s@(w2h,w2l)^T exact i32; fp64 LIF on y2
// with hard margin -> fixup list; z = y1*s3 (bf16).
// Geometry: bc-tile 32 (A rows 128 = 4t x 32), m-tile 64, 4 waves (16 m each,
// all 3 streams), K-step 64, 36 i32x4 accs (no spill).
// OCCUPANCY: 2 x 20KB LDS buffers = 40KB -> 4 blocks/CU (16 waves, 4/SIMD).
// 64B LDS rows, slot swizzle keyed on (row>>1)&3 (0 conflicts measured r7).
// ---------------------------------------------------------------------------
__global__ __launch_bounds__(256, 4) void y12_kernel(
    const int8_t* __restrict__ s8,
    const int8_t* __restrict__ w1q, const int8_t* __restrict__ w2hb,
    const int8_t* __restrict__ w2lb,
    const u16* __restrict__ cnt,
    u16* __restrict__ z,
    uint32_t* __restrict__ fix_cnt,
    int2* __restrict__ fix_idx, float4* __restrict__ fix_y1)
{
    // per-buffer (20480 B): A [0,8192) 128 rows x 64B; B1 [8192,12288);
    // B2h [12288,16384); B2l [16384,20480)
    __shared__ int8_t lds[2][20480];

    const int lane = threadIdx.x & 63;
    const int wid  = threadIdx.x >> 6;

    // XCD-chunked swizzle: nwg = 2352 = 8 * 294
    const int bid = blockIdx.x;
    const int swz = (bid & 7) * 294 + (bid >> 3);
    const int mb  = swz % (NDIM / 64);
    const int rb  = swz / (NDIM / 64);
    const int m0  = mb * 64;
    const int bc0 = rb * 32;

    // ---- staging: 20 chunks of 1KB (16 rows x 64B); 5 per wave ----
    const int srow  = lane >> 2;
    const int scolB = ((lane & 3) ^ ((lane >> 3) & 3)) << 4;
    const int8_t* gp[5];
    int lofs[5];
    #pragma unroll
    for (int c = 0; c < 5; ++c) {
        int chunk = wid * 5 + c;
        const int8_t* g;
        int l;
        if (chunk < 8) {                               // A: 128 rows = t*32+bcl
            int gr = chunk * 16 + srow;
            int t = gr >> 5, bcl = gr & 31;
            g = s8 + ((size_t)(t * BC + bc0 + bcl)) * NDIM + scolB;
            l = chunk * 1024;
        } else if (chunk < 12) {
            int mr = (chunk - 8) * 16 + srow;
            g = w1q + ((size_t)(m0 + mr)) * NDIM + scolB;
            l = 8192 + (chunk - 8) * 1024;
        } else if (chunk < 16) {
            int mr = (chunk - 12) * 16 + srow;
            g = w2hb + ((size_t)(m0 + mr)) * NDIM + scolB;
            l = 12288 + (chunk - 12) * 1024;
        } else {
            int mr = (chunk - 16) * 16 + srow;
            g = w2lb + ((size_t)(m0 + mr)) * NDIM + scolB;
            l = 16384 + (chunk - 16) * 1024;
        }
        gp[c] = g;
        lofs[c] = l;
    }

    // ---- fragment read offsets ----
    const int slotb = (((lane >> 4) ^ ((lane >> 1) & 3)) << 4);
    int aoff[4][2];
    #pragma unroll
    for (int t = 0; t < 4; ++t)
        #pragma unroll
        for (int rt = 0; rt < 2; ++rt)
            aoff[t][rt] = (t * 32 + rt * 16 + (lane & 15)) * 64 + slotb;
    const int boff = (wid * 16 + (lane & 15)) * 64 + slotb;

    i32x4 a1[4][2], ah[4][2], al[4][2];
    #pragma unroll
    for (int t = 0; t < 4; ++t)
        #pragma unroll
        for (int rt = 0; rt < 2; ++rt) {
            a1[t][rt] = (i32x4){0, 0, 0, 0};
            ah[t][rt] = (i32x4){0, 0, 0, 0};
            al[t][rt] = (i32x4){0, 0, 0, 0};
        }

    auto stage = [&](int buf) {
        #pragma unroll
        for (int c = 0; c < 5; ++c) {
            gload16(gp[c], &lds[buf][lofs[c]]);
            gp[c] += 64;                               // next K-64 tile
        }
    };
    auto compute = [&](int buf) {
        const int8_t* L = lds[buf];
        i32x4 b1 = *(const i32x4*)&L[ 8192 + boff];
        i32x4 bh = *(const i32x4*)&L[12288 + boff];
        i32x4 bl = *(const i32x4*)&L[16384 + boff];
        #pragma unroll
        for (int t = 0; t < 4; ++t)
            #pragma unroll
            for (int rt = 0; rt < 2; ++rt) {
                i32x4 a = *(const i32x4*)&L[aoff[t][rt]];
                a1[t][rt] = MFMAI8(a, b1, a1[t][rt]);
                ah[t][rt] = MFMAI8(a, bh, ah[t][rt]);
                al[t][rt] = MFMAI8(a, bl, al[t][rt]);
            }
    };

    // ---- 2-phase dbuf over 12 K-64 tiles ----
    stage(0);
    __syncthreads();
    for (int it = 0; it < 11; ++it) {
        stage((it + 1) & 1);
        compute(it & 1);
        __syncthreads();
    }
    compute(1);

    // ---- epilogue: exact y2_q, fp64 LIF with hard margin, z = y1*s3 ----
    const int mg = m0 + wid * 16 + (lane & 15);
    #pragma unroll
    for (int rt = 0; rt < 2; ++rt) {
        #pragma unroll
        for (int r = 0; r < 4; ++r) {
            const int bcg = bc0 + rt * 16 + (lane >> 4) * 4 + r;
            double v = 0.0, e = 0.0;
            bool flag = false;
            float zv[4], y1v[4];
            #pragma unroll
            for (int t = 0; t < 4; ++t) {
                float y1 = (float)a1[t][rt][r] * (1.0f / 512.0f);
                y1v[t] = y1;
                double y2 = (double)(ah[t][rt][r] * 256 + al[t][rt][r])
                            * (1.0 / 65536.0);
                v = 0.5 * v + y2;
                e = 0.5 * e + 7.62939453125e-6 * (double)cnt[t * BC + bcg] + 1e-9;
                double d = v - 1.0;
                flag |= (d <= e && d >= -e);
                if (v >= 1.0) { zv[t] = y1; v = 0.0; e = 0.0; }
                else          { zv[t] = 0.0f; }
            }
            if (flag) {
                uint32_t id = atomicAdd(fix_cnt, 1u);
                if (id < FIX_CAP) {
                    fix_idx[id] = make_int2(bcg, mg);
                    fix_y1[id]  = make_float4(y1v[0], y1v[1], y1v[2], y1v[3]);
                }
            }
            #pragma unroll
            for (int t = 0; t < 4; ++t)
                z[((size_t)(t * BC + bcg)) * NDIM + mg] = f2b(zv[t]);
        }
    }
}

// ---------------------------------------------------------------------------
// Exact fp64 recompute of flagged (bc,m) pairs; one wave per entry.
// ---------------------------------------------------------------------------
__global__ __launch_bounds__(256) void fixup_kernel(
    const int8_t* __restrict__ s8, const float* __restrict__ w2,
    const int2* __restrict__ fix_idx, const float4* __restrict__ fix_y1,
    const uint32_t* __restrict__ fix_cnt, u16* __restrict__ z)
{
    const int lane = threadIdx.x & 63;
    const int wave = (blockIdx.x * 256 + threadIdx.x) >> 6;
    const int nw   = gridDim.x * 4;
    uint32_t n = *fix_cnt;
    if (n > FIX_CAP) n = FIX_CAP;

    for (uint32_t e = wave; e < n; e += nw) {
        const int bc = fix_idx[e].x, m = fix_idx[e].y;
        const float* w2row = w2 + (size_t)m * NDIM;
        double acc[4] = {0.0, 0.0, 0.0, 0.0};
        #pragma unroll
        for (int j = 0; j < NDIM / 64; ++j) {
            int nn = lane + j * 64;
            double wv = (double)w2row[nn];
            #pragma unroll
            for (int t = 0; t < 4; ++t)
                if (s8[((size_t)(t * BC + bc)) * NDIM + nn]) acc[t] += wv;
        }
        #pragma unroll
        for (int o = 32; o > 0; o >>= 1)
            #pragma unroll
            for (int t = 0; t < 4; ++t) acc[t] += __shfl_xor(acc[t], o);
        if (lane == 0) {
            float4 y1 = fix_y1[e];
            float y1a[4] = {y1.x, y1.y, y1.z, y1.w};
            double v = 0.0;
            #pragma unroll
            for (int t = 0; t < 4; ++t) {
                v = 0.5 * v + acc[t];
                u16 zz = 0;
                if (v >= 1.0) { zz = f2b(y1a[t]); v = 0.0; }
                z[((size_t)(t * BC + bc)) * NDIM + m] = zz;
            }
        }
    }
}

// ---------------------------------------------------------------------------
// Kernel C: out[r][m] = sum_n z[r][n]*w3[m][n], bf16 MFMA, fp32 out.
// 128x128 block tile, 4 waves of 64x64. 2-phase dbuf (round-7 version).
// ---------------------------------------------------------------------------
__global__ __launch_bounds__(256, 2) void out_kernel(
    const u16* __restrict__ z, const u16* __restrict__ w3b,
    float* __restrict__ out)
{
    __shared__ u16 lds[2][16384];  // per-buffer 32KB: Zs [0,8192) Ws [8192,16384)

    const int lane = threadIdx.x & 63;
    const int wid  = threadIdx.x >> 6;
    const int rw   = wid >> 1;     // row-half (64 rows)
    const int cw   = wid & 1;      // col-half (64 m)

    const int bid = blockIdx.x;                        // nwg 1176 = 8*147
    const int swz = (bid & 7) * 147 + (bid >> 3);
    const int mb  = swz % (NDIM / 128);
    const int rb  = swz / (NDIM / 128);
    const int m0  = mb * 128;
    const int r0  = rb * 128;

    const int srow  = lane >> 3;
    const int scolE = ((((lane & 7) << 4) ^ ((srow & 7) << 4)) >> 1);
    const u16* gp[8];
    int lofs[8];
    #pragma unroll
    for (int c = 0; c < 8; ++c) {
        int chunk = wid * 8 + c;
        const u16* g;
        if (chunk < 16) {
            int gr = chunk * 8 + srow;
            g = z + ((size_t)(r0 + gr)) * NDIM + scolE;
        } else {
            int mr = (chunk - 16) * 8 + srow;
            g = w3b + ((size_t)(m0 + mr)) * NDIM + scolE;
        }
        gp[c] = g;
        lofs[c] = chunk * 512;
    }

    const int swzb = (lane & 7) << 4;
    const int cb   = (lane >> 4) << 4;
    const int colE0 = ((cb     ) ^ swzb) >> 1;
    const int colE1 = ((cb | 64) ^ swzb) >> 1;

    f32x4 acc[4][4];               // [rt][cf]
    #pragma unroll
    for (int rt = 0; rt < 4; ++rt)
        #pragma unroll
        for (int cf = 0; cf < 4; ++cf) acc[rt][cf] = (f32x4){0.f, 0.f, 0.f, 0.f};

    auto stage = [&](int buf) {
        #pragma unroll
        for (int c = 0; c < 8; ++c) {
            gload16(gp[c], &lds[buf][lofs[c]]);
            gp[c] += 64;
        }
    };
    auto compute = [&](int buf) {
        const u16* L = lds[buf];
        #pragma unroll
        for (int k2i = 0; k2i < 2; ++k2i) {
            const int ce = k2i ? colE1 : colE0;
            bf16x8 bw[4];
            #pragma unroll
            for (int cf = 0; cf < 4; ++cf)
                bw[cf] = *(const bf16x8*)&L[8192 + (cw * 64 + cf * 16 + (lane & 15)) * 64 + ce];
            #pragma unroll
            for (int rt = 0; rt < 4; ++rt) {
                bf16x8 az = *(const bf16x8*)&L[(rw * 64 + rt * 16 + (lane & 15)) * 64 + ce];
                #pragma unroll
                for (int cf = 0; cf < 4; ++cf)
                    acc[rt][cf] = MFMA16(az, bw[cf], acc[rt][cf]);
            }
        }
    };

    stage(0);
    __syncthreads();
    for (int it = 0; it < 11; ++it) {
        stage((it + 1) & 1);
        compute(it & 1);
        __syncthreads();
    }
    compute(1);

    #pragma unroll
    for (int rt = 0; rt < 4; ++rt)
        #pragma unroll
        for (int cf = 0; cf < 4; ++cf)
            #pragma unroll
            for (int r = 0; r < 4; ++r)
                out[((size_t)(r0 + rw * 64 + rt * 16 + (lane >> 4) * 4 + r)) * NDIM
                    + m0 + cw * 64 + cf * 16 + (lane & 15)] = acc[rt][cf][r];
}

// ---------------------------------------------------------------------------
extern "C" void kernel_launch(void* const* d_in, const int* in_sizes, int n_in,
                              void* d_out, int out_size, void* d_ws, size_t ws_size,
                              hipStream_t stream) {
    const float* x  = (const float*)d_in[0];
    const float* w1 = (const float*)d_in[1];
    const float* w2 = (const float*)d_in[2];
    const float* w3 = (const float*)d_in[3];
    float* out = (float*)d_out;

    char* ws = (char*)d_ws;
    int8_t*   s8      = (int8_t*)(ws);                    // 19,267,584
    u16*      z       = (u16*)(ws + 19267584);            // 38,535,168
    int8_t*   w1q     = (int8_t*)(ws + 57802752);
    int8_t*   w2h     = (int8_t*)(ws + 58392576);
    int8_t*   w2l     = (int8_t*)(ws + 58982400);
    u16*      w3b     = (u16*)(ws + 59572224);
    u16*      cnt     = (u16*)(ws + 60751872);
    uint32_t* fix_cnt = (uint32_t*)(ws + 60802048);
    int2*     fix_idx = (int2*)(ws + 60802112);
    float4*   fix_y1  = (float4*)(ws + 61326400);

    front_kernel<<<BC / 4 + (NDIM * NDIM) / 256, 256, 0, stream>>>(
        x, w1, w2, w3, s8, cnt, w1q, w2h, w2l, w3b, fix_cnt);
    y12_kernel<<<(BC / 32) * (NDIM / 64), 256, 0, stream>>>(s8, w1q, w2h, w2l,
                                                            cnt, z, fix_cnt,
                                                            fix_idx, fix_y1);
    fixup_kernel<<<128, 256, 0, stream>>>(s8, w2, fix_idx, fix_y1, fix_cnt, z);
    out_kernel<<<(TBC / 128) * (NDIM / 128), 256, 0, stream>>>(z, w3b, out);
}

// Round 9
// 142.720 us; speedup vs baseline: 1.1545x; 1.1545x over previous
//
#include <hip/hip_runtime.h>
#include <stdint.h>

// Dims fixed by reference: x [T=4,B=32,C=196,N=768] fp32; w1,w2,w3 [768][768] fp32.
#define T_STEPS 4
#define BC      6272            // B*C
#define NDIM    768
#define TBC     (T_STEPS*BC)    // 25088
#define BCN     (BC*NDIM)
#define FIX_CAP 65536

typedef unsigned short u16;
typedef __attribute__((ext_vector_type(8))) __bf16 bf16x8;
typedef __attribute__((ext_vector_type(4))) float f32x4;
typedef __attribute__((ext_vector_type(4))) int   i32x4;

#define MFMA16(a,b,c)  __builtin_amdgcn_mfma_f32_16x16x32_bf16((a),(b),(c),0,0,0)
#define MFMAI8(a,b,c)  __builtin_amdgcn_mfma_i32_16x16x64_i8((a),(b),(c),0,0,0)

__device__ __forceinline__ u16 f2b(float f) {           // fp32 -> bf16 bits, RNE
    uint32_t u = __builtin_bit_cast(uint32_t, f);
    u += 0x7FFFu + ((u >> 16) & 1u);
    return (u16)(u >> 16);
}
__device__ __forceinline__ void gload16(const void* g, void* l) {
    __builtin_amdgcn_global_load_lds((const __attribute__((address_space(1))) void*)g,
                                     (__attribute__((address_space(3))) void*)l,
                                     16, 0, 0);
}

// ---------------------------------------------------------------------------
// Fused front-end: blocks [0,1568) run lif(x)+counts; blocks [1568,3872) run
// weight prep (w1->i8 x512; w2-> two i8 limbs of round(w2*65536); w3->bf16).
// ---------------------------------------------------------------------------
__global__ __launch_bounds__(256) void front_kernel(
    const float* __restrict__ x,
    const float* __restrict__ w1, const float* __restrict__ w2,
    const float* __restrict__ w3,
    int8_t* __restrict__ s8, u16* __restrict__ cnt,
    int8_t* __restrict__ w1q, int8_t* __restrict__ w2h,
    int8_t* __restrict__ w2l, u16* __restrict__ w3b,
    uint32_t* __restrict__ fix_cnt)
{
    if (blockIdx.x < BC / 4) {
        // ---- LIF over x (fp64) + per-(t,bc) spike counts ----
        const int bc   = blockIdx.x * 4 + (threadIdx.x >> 6);
        const int lane = threadIdx.x & 63;
        const size_t base = (size_t)bc * NDIM + lane * 12;

        double v[12];
        #pragma unroll
        for (int j = 0; j < 12; ++j) v[j] = 0.0;
        uint32_t c01 = 0, c23 = 0;

        #pragma unroll
        for (int t = 0; t < T_STEPS; ++t) {
            float4 xa = *(const float4*)&x[(size_t)t * BCN + base + 0];
            float4 xb = *(const float4*)&x[(size_t)t * BCN + base + 4];
            float4 xc = *(const float4*)&x[(size_t)t * BCN + base + 8];
            float xs[12] = {xa.x, xa.y, xa.z, xa.w, xb.x, xb.y, xb.z, xb.w,
                            xc.x, xc.y, xc.z, xc.w};
            uint32_t pk[3] = {0, 0, 0};
            uint32_t csum = 0;
            #pragma unroll
            for (int j = 0; j < 12; ++j) {
                v[j] = 0.5 * v[j] + (double)xs[j];
                if (v[j] >= 1.0) {
                    pk[j >> 2] |= 1u << ((j & 3) * 8);
                    csum++;
                    v[j] = 0.0;
                }
            }
            uint32_t* dst = (uint32_t*)&s8[(size_t)t * BCN + base];
            dst[0] = pk[0]; dst[1] = pk[1]; dst[2] = pk[2];
            if (t < 2) c01 += csum << (t * 16);
            else       c23 += csum << ((t - 2) * 16);
        }
        #pragma unroll
        for (int o = 32; o > 0; o >>= 1) {
            c01 += __shfl_xor(c01, o);
            c23 += __shfl_xor(c23, o);
        }
        if (lane == 0) {
            cnt[0 * BC + bc] = (u16)(c01 & 0xFFFF);
            cnt[1 * BC + bc] = (u16)(c01 >> 16);
            cnt[2 * BC + bc] = (u16)(c23 & 0xFFFF);
            cnt[3 * BC + bc] = (u16)(c23 >> 16);
        }
    } else {
        // ---- weight prep ----
        int i = (blockIdx.x - BC / 4) * 256 + threadIdx.x;  // [0, 768*768)
        if (i == 0) *fix_cnt = 0;
        int q1 = __float2int_rn(w1[i] * 512.0f);
        q1 = q1 > 127 ? 127 : (q1 < -127 ? -127 : q1);
        w1q[i] = (int8_t)q1;
        int q16 = __double2int_rn((double)w2[i] * 65536.0);
        int8_t lo = (int8_t)(q16 & 0xFF);
        int hi = (q16 - (int)lo) >> 8;                      // exact split
        w2h[i] = (int8_t)hi;
        w2l[i] = lo;
        w3b[i] = f2b(w3[i]);
    }
}

// ---------------------------------------------------------------------------
// Kernel B (i8): y1 = s@w1q^T, y2 = s@(w2h,w2l)^T exact i32; fp64 LIF on y2
// with hard margin -> fixup list; z = y1*s3 (bf16).
// REGISTER-LEAN geometry: bc-tile 16 (A rows 64 = 4t x 16), m-tile 64,
// 4 waves (16 m each, 3 streams). Accs = 12 i32x4 = 48 regs (was 144) ->
// ~4 waves/SIMD resident. LDS 2 x 16KB = 32KB. K-step 64.
// 64B LDS rows, slot swizzle keyed on (row>>1)&3 (0 conflicts, r7/r8).
// ---------------------------------------------------------------------------
__global__ __launch_bounds__(256, 3) void y12_kernel(
    const int8_t* __restrict__ s8,
    const int8_t* __restrict__ w1q, const int8_t* __restrict__ w2hb,
    const int8_t* __restrict__ w2lb,
    const u16* __restrict__ cnt,
    u16* __restrict__ z,
    uint32_t* __restrict__ fix_cnt,
    int2* __restrict__ fix_idx, float4* __restrict__ fix_y1)
{
    // per-buffer (16384 B): A [0,4096) 64 rows x 64B; B1 [4096,8192);
    // B2h [8192,12288); B2l [12288,16384)
    __shared__ int8_t lds[2][16384];

    const int lane = threadIdx.x & 63;
    const int wid  = threadIdx.x >> 6;

    // XCD-chunked swizzle: nwg = 4704 = 8 * 588
    const int bid = blockIdx.x;
    const int swz = (bid & 7) * 588 + (bid >> 3);
    const int mb  = swz % (NDIM / 64);
    const int rb  = swz / (NDIM / 64);
    const int m0  = mb * 64;
    const int bc0 = rb * 16;

    // ---- staging: 16 chunks of 1KB (16 rows x 64B); 4 per wave ----
    const int srow  = lane >> 2;
    const int scolB = ((lane & 3) ^ ((lane >> 3) & 3)) << 4;
    const int8_t* gp[4];
    int lofs[4];
    #pragma unroll
    for (int c = 0; c < 4; ++c) {
        int chunk = wid * 4 + c;
        const int8_t* g;
        int l;
        if (chunk < 4) {                               // A: 64 rows = t*16+bcl
            int gr = chunk * 16 + srow;
            int t = gr >> 4, bcl = gr & 15;
            g = s8 + ((size_t)(t * BC + bc0 + bcl)) * NDIM + scolB;
            l = chunk * 1024;
        } else if (chunk < 8) {
            int mr = (chunk - 4) * 16 + srow;
            g = w1q + ((size_t)(m0 + mr)) * NDIM + scolB;
            l = 4096 + (chunk - 4) * 1024;
        } else if (chunk < 12) {
            int mr = (chunk - 8) * 16 + srow;
            g = w2hb + ((size_t)(m0 + mr)) * NDIM + scolB;
            l = 8192 + (chunk - 8) * 1024;
        } else {
            int mr = (chunk - 12) * 16 + srow;
            g = w2lb + ((size_t)(m0 + mr)) * NDIM + scolB;
            l = 12288 + (chunk - 12) * 1024;
        }
        gp[c] = g;
        lofs[c] = l;
    }

    // ---- fragment read offsets ----
    const int slotb = (((lane >> 4) ^ ((lane >> 1) & 3)) << 4);
    int aoff[4];
    #pragma unroll
    for (int t = 0; t < 4; ++t)
        aoff[t] = (t * 16 + (lane & 15)) * 64 + slotb;
    const int boff = (wid * 16 + (lane & 15)) * 64 + slotb;

    i32x4 a1[4], ah[4], al[4];
    #pragma unroll
    for (int t = 0; t < 4; ++t) {
        a1[t] = (i32x4){0, 0, 0, 0};
        ah[t] = (i32x4){0, 0, 0, 0};
        al[t] = (i32x4){0, 0, 0, 0};
    }

    auto stage = [&](int buf) {
        #pragma unroll
        for (int c = 0; c < 4; ++c) {
            gload16(gp[c], &lds[buf][lofs[c]]);
            gp[c] += 64;                               // next K-64 tile
        }
    };
    auto compute = [&](int buf) {
        const int8_t* L = lds[buf];
        i32x4 b1 = *(const i32x4*)&L[ 4096 + boff];
        i32x4 bh = *(const i32x4*)&L[ 8192 + boff];
        i32x4 bl = *(const i32x4*)&L[12288 + boff];
        #pragma unroll
        for (int t = 0; t < 4; ++t) {
            i32x4 a = *(const i32x4*)&L[aoff[t]];
            a1[t] = MFMAI8(a, b1, a1[t]);
            ah[t] = MFMAI8(a, bh, ah[t]);
            al[t] = MFMAI8(a, bl, al[t]);
        }
    };

    // ---- 2-phase dbuf over 12 K-64 tiles ----
    stage(0);
    __syncthreads();
    for (int it = 0; it < 11; ++it) {
        stage((it + 1) & 1);
        compute(it & 1);
        __syncthreads();
    }
    compute(1);

    // ---- epilogue: exact y2_q, fp64 LIF with hard margin, z = y1*s3 ----
    const int mg = m0 + wid * 16 + (lane & 15);
    #pragma unroll
    for (int r = 0; r < 4; ++r) {
        const int bcg = bc0 + (lane >> 4) * 4 + r;
        double v = 0.0, e = 0.0;
        bool flag = false;
        float zv[4], y1v[4];
        #pragma unroll
        for (int t = 0; t < 4; ++t) {
            float y1 = (float)a1[t][r] * (1.0f / 512.0f);
            y1v[t] = y1;
            double y2 = (double)(ah[t][r] * 256 + al[t][r]) * (1.0 / 65536.0);
            v = 0.5 * v + y2;
            e = 0.5 * e + 7.62939453125e-6 * (double)cnt[t * BC + bcg] + 1e-9;
            double d = v - 1.0;
            flag |= (d <= e && d >= -e);
            if (v >= 1.0) { zv[t] = y1; v = 0.0; e = 0.0; }
            else          { zv[t] = 0.0f; }
        }
        if (flag) {
            uint32_t id = atomicAdd(fix_cnt, 1u);
            if (id < FIX_CAP) {
                fix_idx[id] = make_int2(bcg, mg);
                fix_y1[id]  = make_float4(y1v[0], y1v[1], y1v[2], y1v[3]);
            }
        }
        #pragma unroll
        for (int t = 0; t < 4; ++t)
            z[((size_t)(t * BC + bcg)) * NDIM + mg] = f2b(zv[t]);
    }
}

// ---------------------------------------------------------------------------
// Exact fp64 recompute of flagged (bc,m) pairs; one wave per entry.
// ---------------------------------------------------------------------------
__global__ __launch_bounds__(256) void fixup_kernel(
    const int8_t* __restrict__ s8, const float* __restrict__ w2,
    const int2* __restrict__ fix_idx, const float4* __restrict__ fix_y1,
    const uint32_t* __restrict__ fix_cnt, u16* __restrict__ z)
{
    const int lane = threadIdx.x & 63;
    const int wave = (blockIdx.x * 256 + threadIdx.x) >> 6;
    const int nw   = gridDim.x * 4;
    uint32_t n = *fix_cnt;
    if (n > FIX_CAP) n = FIX_CAP;

    for (uint32_t e = wave; e < n; e += nw) {
        const int bc = fix_idx[e].x, m = fix_idx[e].y;
        const float* w2row = w2 + (size_t)m * NDIM;
        double acc[4] = {0.0, 0.0, 0.0, 0.0};
        #pragma unroll
        for (int j = 0; j < NDIM / 64; ++j) {
            int nn = lane + j * 64;
            double wv = (double)w2row[nn];
            #pragma unroll
            for (int t = 0; t < 4; ++t)
                if (s8[((size_t)(t * BC + bc)) * NDIM + nn]) acc[t] += wv;
        }
        #pragma unroll
        for (int o = 32; o > 0; o >>= 1)
            #pragma unroll
            for (int t = 0; t < 4; ++t) acc[t] += __shfl_xor(acc[t], o);
        if (lane == 0) {
            float4 y1 = fix_y1[e];
            float y1a[4] = {y1.x, y1.y, y1.z, y1.w};
            double v = 0.0;
            #pragma unroll
            for (int t = 0; t < 4; ++t) {
                v = 0.5 * v + acc[t];
                u16 zz = 0;
                if (v >= 1.0) { zz = f2b(y1a[t]); v = 0.0; }
                z[((size_t)(t * BC + bc)) * NDIM + m] = zz;
            }
        }
    }
}

// ---------------------------------------------------------------------------
// Kernel C: out[r][m] = sum_n z[r][n]*w3[m][n], bf16 MFMA, fp32 out.
// 128x128 block tile, 4 waves of 64x64. 2-phase dbuf.
// ---------------------------------------------------------------------------
__global__ __launch_bounds__(256, 2) void out_kernel(
    const u16* __restrict__ z, const u16* __restrict__ w3b,
    float* __restrict__ out)
{
    __shared__ u16 lds[2][16384];  // per-buffer 32KB: Zs [0,8192) Ws [8192,16384)

    const int lane = threadIdx.x & 63;
    const int wid  = threadIdx.x >> 6;
    const int rw   = wid >> 1;     // row-half (64 rows)
    const int cw   = wid & 1;      // col-half (64 m)

    const int bid = blockIdx.x;                        // nwg 1176 = 8*147
    const int swz = (bid & 7) * 147 + (bid >> 3);
    const int mb  = swz % (NDIM / 128);
    const int rb  = swz / (NDIM / 128);
    const int m0  = mb * 128;
    const int r0  = rb * 128;

    const int srow  = lane >> 3;
    const int scolE = ((((lane & 7) << 4) ^ ((srow & 7) << 4)) >> 1);
    const u16* gp[8];
    int lofs[8];
    #pragma unroll
    for (int c = 0; c < 8; ++c) {
        int chunk = wid * 8 + c;
        const u16* g;
        if (chunk < 16) {
            int gr = chunk * 8 + srow;
            g = z + ((size_t)(r0 + gr)) * NDIM + scolE;
        } else {
            int mr = (chunk - 16) * 8 + srow;
            g = w3b + ((size_t)(m0 + mr)) * NDIM + scolE;
        }
        gp[c] = g;
        lofs[c] = chunk * 512;
    }

    const int swzb = (lane & 7) << 4;
    const int cb   = (lane >> 4) << 4;
    const int colE0 = ((cb     ) ^ swzb) >> 1;
    const int colE1 = ((cb | 64) ^ swzb) >> 1;

    f32x4 acc[4][4];               // [rt][cf]
    #pragma unroll
    for (int rt = 0; rt < 4; ++rt)
        #pragma unroll
        for (int cf = 0; cf < 4; ++cf) acc[rt][cf] = (f32x4){0.f, 0.f, 0.f, 0.f};

    auto stage = [&](int buf) {
        #pragma unroll
        for (int c = 0; c < 8; ++c) {
            gload16(gp[c], &lds[buf][lofs[c]]);
            gp[c] += 64;
        }
    };
    auto compute = [&](int buf) {
        const u16* L = lds[buf];
        #pragma unroll
        for (int k2i = 0; k2i < 2; ++k2i) {
            const int ce = k2i ? colE1 : colE0;
            bf16x8 bw[4];
            #pragma unroll
            for (int cf = 0; cf < 4; ++cf)
                bw[cf] = *(const bf16x8*)&L[8192 + (cw * 64 + cf * 16 + (lane & 15)) * 64 + ce];
            #pragma unroll
            for (int rt = 0; rt < 4; ++rt) {
                bf16x8 az = *(const bf16x8*)&L[(rw * 64 + rt * 16 + (lane & 15)) * 64 + ce];
                #pragma unroll
                for (int cf = 0; cf < 4; ++cf)
                    acc[rt][cf] = MFMA16(az, bw[cf], acc[rt][cf]);
            }
        }
    };

    stage(0);
    __syncthreads();
    for (int it = 0; it < 11; ++it) {
        stage((it + 1) & 1);
        compute(it & 1);
        __syncthreads();
    }
    compute(1);

    #pragma unroll
    for (int rt = 0; rt < 4; ++rt)
        #pragma unroll
        for (int cf = 0; cf < 4; ++cf)
            #pragma unroll
            for (int r = 0; r < 4; ++r)
                out[((size_t)(r0 + rw * 64 + rt * 16 + (lane >> 4) * 4 + r)) * NDIM
                    + m0 + cw * 64 + cf * 16 + (lane & 15)] = acc[rt][cf][r];
}

// ---------------------------------------------------------------------------
extern "C" void kernel_launch(void* const* d_in, const int* in_sizes, int n_in,
                              void* d_out, int out_size, void* d_ws, size_t ws_size,
                              hipStream_t stream) {
    const float* x  = (const float*)d_in[0];
    const float* w1 = (const float*)d_in[1];
    const float* w2 = (const float*)d_in[2];
    const float* w3 = (const float*)d_in[3];
    float* out = (float*)d_out;

    char* ws = (char*)d_ws;
    int8_t*   s8      = (int8_t*)(ws);                    // 19,267,584
    u16*      z       = (u16*)(ws + 19267584);            // 38,535,168
    int8_t*   w1q     = (int8_t*)(ws + 57802752);
    int8_t*   w2h     = (int8_t*)(ws + 58392576);
    int8_t*   w2l     = (int8_t*)(ws + 58982400);
    u16*      w3b     = (u16*)(ws + 59572224);
    u16*      cnt     = (u16*)(ws + 60751872);
    uint32_t* fix_cnt = (uint32_t*)(ws + 60802048);
    int2*     fix_idx = (int2*)(ws + 60802112);
    float4*   fix_y1  = (float4*)(ws + 61326400);

    front_kernel<<<BC / 4 + (NDIM * NDIM) / 256, 256, 0, stream>>>(
        x, w1, w2, w3, s8, cnt, w1q, w2h, w2l, w3b, fix_cnt);
    y12_kernel<<<(BC / 16) * (NDIM / 64), 256, 0, stream>>>(s8, w1q, w2h, w2l,
                                                            cnt, z, fix_cnt,
                                                            fix_idx, fix_y1);
    fixup_kernel<<<128, 256, 0, stream>>>(s8, w2, fix_idx, fix_y1, fix_cnt, z);
    out_kernel<<<(TBC / 128) * (NDIM / 128), 256, 0, stream>>>(z, w3b, out);
}

// Round 10
// 120.813 us; speedup vs baseline: 1.3638x; 1.1813x over previous
//
#include <hip/hip_runtime.h>
#include <stdint.h>

// Dims fixed by reference: x [T=4,B=32,C=196,N=768] fp32; w1,w2,w3 [768][768] fp32.
#define T_STEPS 4
#define BC      6272            // B*C
#define NDIM    768
#define TBC     (T_STEPS*BC)    // 25088
#define BCN     (BC*NDIM)
#define FIX_CAP 65536

typedef unsigned short u16;
typedef __attribute__((ext_vector_type(8))) __bf16 bf16x8;
typedef __attribute__((ext_vector_type(4))) float f32x4;
typedef __attribute__((ext_vector_type(4))) int   i32x4;

#define MFMA16(a,b,c)  __builtin_amdgcn_mfma_f32_16x16x32_bf16((a),(b),(c),0,0,0)
#define MFMAI8(a,b,c)  __builtin_amdgcn_mfma_i32_16x16x64_i8((a),(b),(c),0,0,0)

__device__ __forceinline__ u16 f2b(float f) {           // fp32 -> bf16 bits, RNE
    uint32_t u = __builtin_bit_cast(uint32_t, f);
    u += 0x7FFFu + ((u >> 16) & 1u);
    return (u16)(u >> 16);
}
__device__ __forceinline__ void gload16(const void* g, void* l) {
    __builtin_amdgcn_global_load_lds((const __attribute__((address_space(1))) void*)g,
                                     (__attribute__((address_space(3))) void*)l,
                                     16, 0, 0);
}

// ---------------------------------------------------------------------------
// Fused front-end: blocks [0,1568) run lif(x)+counts; blocks [1568,3872) run
// weight prep (w1->i8 x512; w2-> two i8 limbs of round(w2*65536); w3->bf16).
// ---------------------------------------------------------------------------
__global__ __launch_bounds__(256) void front_kernel(
    const float* __restrict__ x,
    const float* __restrict__ w1, const float* __restrict__ w2,
    const float* __restrict__ w3,
    int8_t* __restrict__ s8, u16* __restrict__ cnt,
    int8_t* __restrict__ w1q, int8_t* __restrict__ w2h,
    int8_t* __restrict__ w2l, u16* __restrict__ w3b,
    uint32_t* __restrict__ fix_cnt)
{
    if (blockIdx.x < BC / 4) {
        // ---- LIF over x (fp64) + per-(t,bc) spike counts ----
        const int bc   = blockIdx.x * 4 + (threadIdx.x >> 6);
        const int lane = threadIdx.x & 63;
        const size_t base = (size_t)bc * NDIM + lane * 12;

        double v[12];
        #pragma unroll
        for (int j = 0; j < 12; ++j) v[j] = 0.0;
        uint32_t c01 = 0, c23 = 0;

        #pragma unroll
        for (int t = 0; t < T_STEPS; ++t) {
            float4 xa = *(const float4*)&x[(size_t)t * BCN + base + 0];
            float4 xb = *(const float4*)&x[(size_t)t * BCN + base + 4];
            float4 xc = *(const float4*)&x[(size_t)t * BCN + base + 8];
            float xs[12] = {xa.x, xa.y, xa.z, xa.w, xb.x, xb.y, xb.z, xb.w,
                            xc.x, xc.y, xc.z, xc.w};
            uint32_t pk[3] = {0, 0, 0};
            uint32_t csum = 0;
            #pragma unroll
            for (int j = 0; j < 12; ++j) {
                v[j] = 0.5 * v[j] + (double)xs[j];
                if (v[j] >= 1.0) {
                    pk[j >> 2] |= 1u << ((j & 3) * 8);
                    csum++;
                    v[j] = 0.0;
                }
            }
            uint32_t* dst = (uint32_t*)&s8[(size_t)t * BCN + base];
            dst[0] = pk[0]; dst[1] = pk[1]; dst[2] = pk[2];
            if (t < 2) c01 += csum << (t * 16);
            else       c23 += csum << ((t - 2) * 16);
        }
        #pragma unroll
        for (int o = 32; o > 0; o >>= 1) {
            c01 += __shfl_xor(c01, o);
            c23 += __shfl_xor(c23, o);
        }
        if (lane == 0) {
            cnt[0 * BC + bc] = (u16)(c01 & 0xFFFF);
            cnt[1 * BC + bc] = (u16)(c01 >> 16);
            cnt[2 * BC + bc] = (u16)(c23 & 0xFFFF);
            cnt[3 * BC + bc] = (u16)(c23 >> 16);
        }
    } else {
        // ---- weight prep ----
        int i = (blockIdx.x - BC / 4) * 256 + threadIdx.x;  // [0, 768*768)
        if (i == 0) *fix_cnt = 0;
        int q1 = __float2int_rn(w1[i] * 512.0f);
        q1 = q1 > 127 ? 127 : (q1 < -127 ? -127 : q1);
        w1q[i] = (int8_t)q1;
        int q16 = __double2int_rn((double)w2[i] * 65536.0);
        int8_t lo = (int8_t)(q16 & 0xFF);
        int hi = (q16 - (int)lo) >> 8;                      // exact split
        w2h[i] = (int8_t)hi;
        w2l[i] = lo;
        w3b[i] = f2b(w3[i]);
    }
}

// ---------------------------------------------------------------------------
// Kernel B (i8) — ROUND-5 VERBATIM (empirical best, 65.3 µs):
// y1 = s@w1q^T, y2 = s@(w2h,w2l)^T exact i32; fp64 LIF on y2 with hard
// margin -> fixup list; z = y1*s3 (bf16).
// Block: bc-tile 32 (A rows 128 = 4t x 32), m-tile 64, 4 waves (16 m each).
// K-step 128 (two K=64 subtiles/row). LDS rows 128B, XOR-swizzled (row&7);
// 40KB/buf x2 = 80KB, 2-phase dbuf.
// ---------------------------------------------------------------------------
__global__ __launch_bounds__(256) void y12_kernel(
    const int8_t* __restrict__ s8,
    const int8_t* __restrict__ w1q, const int8_t* __restrict__ w2hb,
    const int8_t* __restrict__ w2lb,
    const u16* __restrict__ cnt,
    u16* __restrict__ z,
    uint32_t* __restrict__ fix_cnt,
    int2* __restrict__ fix_idx, float4* __restrict__ fix_y1)
{
    // per-buffer: A [0,16384) 128x128B; B1 [16384,24576); B2h [24576,32768);
    // B2l [32768,40960)
    __shared__ int8_t lds[2][40960];

    const int tid  = threadIdx.x;
    const int lane = tid & 63;
    const int wid  = tid >> 6;

    // XCD-chunked swizzle: nwg = 2352 = 8 * 294
    const int bid = blockIdx.x;
    const int swz = (bid & 7) * 294 + (bid >> 3);
    const int mb  = swz % (NDIM / 64);
    const int rb  = swz / (NDIM / 64);
    const int m0  = mb * 64;
    const int bc0 = rb * 32;

    // ---- staging: 40 chunks of 1KB (8 rows x 128B); 10 per wave ----
    const int srow  = lane >> 3;                       // row in 8-row chunk
    const int scolB = ((lane & 7) << 4) ^ (srow << 4); // pre-swizzled src byte col
    const int8_t* gp[10];
    int lofs[10];
    #pragma unroll
    for (int c = 0; c < 10; ++c) {
        int chunk = wid * 10 + c;
        const int8_t* g;
        int l;
        if (chunk < 16) {                              // A: 128 rows = t*32+bcl
            int gr = chunk * 8 + srow;
            int t = gr >> 5, bcl = gr & 31;
            g = s8 + ((size_t)(t * BC + bc0 + bcl)) * NDIM + scolB;
            l = chunk * 1024;
        } else if (chunk < 24) {
            int mr = (chunk - 16) * 8 + srow;
            g = w1q + ((size_t)(m0 + mr)) * NDIM + scolB;
            l = 16384 + (chunk - 16) * 1024;
        } else if (chunk < 32) {
            int mr = (chunk - 24) * 8 + srow;
            g = w2hb + ((size_t)(m0 + mr)) * NDIM + scolB;
            l = 24576 + (chunk - 24) * 1024;
        } else {
            int mr = (chunk - 32) * 8 + srow;
            g = w2lb + ((size_t)(m0 + mr)) * NDIM + scolB;
            l = 32768 + (chunk - 32) * 1024;
        }
        gp[c] = g;
        lofs[c] = l;
    }

    // ---- fragment read offsets ----
    const int key = lane & 7;
    const int g4  = lane >> 4;                         // k-group 0..3
    int slotA[2];
    slotA[0] = ((g4     ^ key) << 4);                  // ks=0: slots 0..3
    slotA[1] = (((4|g4) ^ key) << 4);                  // ks=1: slots 4..7
    int abase[8];
    #pragma unroll
    for (int t = 0; t < 4; ++t)
        #pragma unroll
        for (int rt = 0; rt < 2; ++rt)
            abase[t * 2 + rt] = (t * 32 + rt * 16 + (lane & 15)) * 128;
    const int bbase = (wid * 16 + (lane & 15)) * 128;

    i32x4 acc1[4][2], acch[4][2], accl[4][2];
    #pragma unroll
    for (int t = 0; t < 4; ++t)
        #pragma unroll
        for (int rt = 0; rt < 2; ++rt) {
            acc1[t][rt] = (i32x4){0, 0, 0, 0};
            acch[t][rt] = (i32x4){0, 0, 0, 0};
            accl[t][rt] = (i32x4){0, 0, 0, 0};
        }

    auto stage = [&](int buf) {
        #pragma unroll
        for (int c = 0; c < 10; ++c) {
            gload16(gp[c], &lds[buf][lofs[c]]);
            gp[c] += 128;
        }
    };
    auto compute = [&](int buf) {
        const int8_t* L = lds[buf];
        #pragma unroll
        for (int ks = 0; ks < 2; ++ks) {
            const int sl = slotA[ks];
            i32x4 b1 = *(const i32x4*)&L[16384 + bbase + sl];
            i32x4 bh = *(const i32x4*)&L[24576 + bbase + sl];
            i32x4 bl = *(const i32x4*)&L[32768 + bbase + sl];
            #pragma unroll
            for (int t = 0; t < 4; ++t)
                #pragma unroll
                for (int rt = 0; rt < 2; ++rt) {
                    i32x4 a = *(const i32x4*)&L[abase[t * 2 + rt] + sl];
                    acc1[t][rt] = MFMAI8(a, b1, acc1[t][rt]);
                    acch[t][rt] = MFMAI8(a, bh, acch[t][rt]);
                    accl[t][rt] = MFMAI8(a, bl, accl[t][rt]);
                }
        }
    };

    // ---- 2-phase dbuf over 6 K-128 tiles ----
    stage(0);
    __syncthreads();
    #pragma unroll
    for (int it = 0; it < 5; ++it) {
        stage((it + 1) & 1);
        compute(it & 1);
        __syncthreads();
    }
    compute(1);

    // ---- epilogue: exact y2_q, fp64 LIF with hard margin, z = y1*s3 ----
    const int mg = m0 + wid * 16 + (lane & 15);
    #pragma unroll
    for (int rt = 0; rt < 2; ++rt) {
        #pragma unroll
        for (int r = 0; r < 4; ++r) {
            const int bcg = bc0 + rt * 16 + (lane >> 4) * 4 + r;
            double v = 0.0, e = 0.0;
            bool flag = false;
            float zv[4], y1v[4];
            #pragma unroll
            for (int t = 0; t < 4; ++t) {
                float y1 = (float)acc1[t][rt][r] * (1.0f / 512.0f);
                y1v[t] = y1;
                double y2 = (double)(acch[t][rt][r] * 256 + accl[t][rt][r])
                            * (1.0 / 65536.0);
                v = 0.5 * v + y2;
                e = 0.5 * e + 7.62939453125e-6 * (double)cnt[t * BC + bcg] + 1e-9;
                double d = v - 1.0;
                flag |= (d <= e && d >= -e);
                if (v >= 1.0) { zv[t] = y1; v = 0.0; e = 0.0; }
                else          { zv[t] = 0.0f; }
            }
            if (flag) {
                uint32_t id = atomicAdd(fix_cnt, 1u);
                if (id < FIX_CAP) {
                    fix_idx[id] = make_int2(bcg, mg);
                    fix_y1[id]  = make_float4(y1v[0], y1v[1], y1v[2], y1v[3]);
                }
            }
            #pragma unroll
            for (int t = 0; t < 4; ++t)
                z[((size_t)(t * BC + bcg)) * NDIM + mg] = f2b(zv[t]);
        }
    }
}

// ---------------------------------------------------------------------------
// Exact fp64 recompute of flagged (bc,m) pairs; one wave per entry.
// Grid enlarged to 512 blocks (2048 waves) — fixup was a serial ~15-20 µs
// stage between y12 and out at 128 blocks.
// ---------------------------------------------------------------------------
__global__ __launch_bounds__(256) void fixup_kernel(
    const int8_t* __restrict__ s8, const float* __restrict__ w2,
    const int2* __restrict__ fix_idx, const float4* __restrict__ fix_y1,
    const uint32_t* __restrict__ fix_cnt, u16* __restrict__ z)
{
    const int lane = threadIdx.x & 63;
    const int wave = (blockIdx.x * 256 + threadIdx.x) >> 6;
    const int nw   = gridDim.x * 4;
    uint32_t n = *fix_cnt;
    if (n > FIX_CAP) n = FIX_CAP;

    for (uint32_t e = wave; e < n; e += nw) {
        const int bc = fix_idx[e].x, m = fix_idx[e].y;
        const float* w2row = w2 + (size_t)m * NDIM;
        double acc[4] = {0.0, 0.0, 0.0, 0.0};
        #pragma unroll
        for (int j = 0; j < NDIM / 64; ++j) {
            int nn = lane + j * 64;
            double wv = (double)w2row[nn];
            #pragma unroll
            for (int t = 0; t < 4; ++t)
                if (s8[((size_t)(t * BC + bc)) * NDIM + nn]) acc[t] += wv;
        }
        #pragma unroll
        for (int o = 32; o > 0; o >>= 1)
            #pragma unroll
            for (int t = 0; t < 4; ++t) acc[t] += __shfl_xor(acc[t], o);
        if (lane == 0) {
            float4 y1 = fix_y1[e];
            float y1a[4] = {y1.x, y1.y, y1.z, y1.w};
            double v = 0.0;
            #pragma unroll
            for (int t = 0; t < 4; ++t) {
                v = 0.5 * v + acc[t];
                u16 zz = 0;
                if (v >= 1.0) { zz = f2b(y1a[t]); v = 0.0; }
                z[((size_t)(t * BC + bc)) * NDIM + m] = zz;
            }
        }
    }
}

// ---------------------------------------------------------------------------
// Kernel C: out[r][m] = sum_n z[r][n]*w3[m][n], bf16 MFMA, fp32 out.
// 128x128 block tile, 4 waves of 64x64. 2-phase dbuf.
// ---------------------------------------------------------------------------
__global__ __launch_bounds__(256, 2) void out_kernel(
    const u16* __restrict__ z, const u16* __restrict__ w3b,
    float* __restrict__ out)
{
    __shared__ u16 lds[2][16384];  // per-buffer 32KB: Zs [0,8192) Ws [8192,16384)

    const int lane = threadIdx.x & 63;
    const int wid  = threadIdx.x >> 6;
    const int rw   = wid >> 1;     // row-half (64 rows)
    const int cw   = wid & 1;      // col-half (64 m)

    const int bid = blockIdx.x;                        // nwg 1176 = 8*147
    const int swz = (bid & 7) * 147 + (bid >> 3);
    const int mb  = swz % (NDIM / 128);
    const int rb  = swz / (NDIM / 128);
    const int m0  = mb * 128;
    const int r0  = rb * 128;

    const int srow  = lane >> 3;
    const int scolE = ((((lane & 7) << 4) ^ ((srow & 7) << 4)) >> 1);
    const u16* gp[8];
    int lofs[8];
    #pragma unroll
    for (int c = 0; c < 8; ++c) {
        int chunk = wid * 8 + c;
        const u16* g;
        if (chunk < 16) {
            int gr = chunk * 8 + srow;
            g = z + ((size_t)(r0 + gr)) * NDIM + scolE;
        } else {
            int mr = (chunk - 16) * 8 + srow;
            g = w3b + ((size_t)(m0 + mr)) * NDIM + scolE;
        }
        gp[c] = g;
        lofs[c] = chunk * 512;
    }

    const int swzb = (lane & 7) << 4;
    const int cb   = (lane >> 4) << 4;
    const int colE0 = ((cb     ) ^ swzb) >> 1;
    const int colE1 = ((cb | 64) ^ swzb) >> 1;

    f32x4 acc[4][4];               // [rt][cf]
    #pragma unroll
    for (int rt = 0; rt < 4; ++rt)
        #pragma unroll
        for (int cf = 0; cf < 4; ++cf) acc[rt][cf] = (f32x4){0.f, 0.f, 0.f, 0.f};

    auto stage = [&](int buf) {
        #pragma unroll
        for (int c = 0; c < 8; ++c) {
            gload16(gp[c], &lds[buf][lofs[c]]);
            gp[c] += 64;
        }
    };
    auto compute = [&](int buf) {
        const u16* L = lds[buf];
        #pragma unroll
        for (int k2i = 0; k2i < 2; ++k2i) {
            const int ce = k2i ? colE1 : colE0;
            bf16x8 bw[4];
            #pragma unroll
            for (int cf = 0; cf < 4; ++cf)
                bw[cf] = *(const bf16x8*)&L[8192 + (cw * 64 + cf * 16 + (lane & 15)) * 64 + ce];
            #pragma unroll
            for (int rt = 0; rt < 4; ++rt) {
                bf16x8 az = *(const bf16x8*)&L[(rw * 64 + rt * 16 + (lane & 15)) * 64 + ce];
                #pragma unroll
                for (int cf = 0; cf < 4; ++cf)
                    acc[rt][cf] = MFMA16(az, bw[cf], acc[rt][cf]);
            }
        }
    };

    stage(0);
    __syncthreads();
    for (int it = 0; it < 11; ++it) {
        stage((it + 1) & 1);
        compute(it & 1);
        __syncthreads();
    }
    compute(1);

    #pragma unroll
    for (int rt = 0; rt < 4; ++rt)
        #pragma unroll
        for (int cf = 0; cf < 4; ++cf)
            #pragma unroll
            for (int r = 0; r < 4; ++r)
                out[((size_t)(r0 + rw * 64 + rt * 16 + (lane >> 4) * 4 + r)) * NDIM
                    + m0 + cw * 64 + cf * 16 + (lane & 15)] = acc[rt][cf][r];
}

// ---------------------------------------------------------------------------
extern "C" void kernel_launch(void* const* d_in, const int* in_sizes, int n_in,
                              void* d_out, int out_size, void* d_ws, size_t ws_size,
                              hipStream_t stream) {
    const float* x  = (const float*)d_in[0];
    const float* w1 = (const float*)d_in[1];
    const float* w2 = (const float*)d_in[2];
    const float* w3 = (const float*)d_in[3];
    float* out = (float*)d_out;

    char* ws = (char*)d_ws;
    int8_t*   s8      = (int8_t*)(ws);                    // 19,267,584
    u16*      z       = (u16*)(ws + 19267584);            // 38,535,168
    int8_t*   w1q     = (int8_t*)(ws + 57802752);
    int8_t*   w2h     = (int8_t*)(ws + 58392576);
    int8_t*   w2l     = (int8_t*)(ws + 58982400);
    u16*      w3b     = (u16*)(ws + 59572224);
    u16*      cnt     = (u16*)(ws + 60751872);
    uint32_t* fix_cnt = (uint32_t*)(ws + 60802048);
    int2*     fix_idx = (int2*)(ws + 60802112);
    float4*   fix_y1  = (float4*)(ws + 61326400);

    front_kernel<<<BC / 4 + (NDIM * NDIM) / 256, 256, 0, stream>>>(
        x, w1, w2, w3, s8, cnt, w1q, w2h, w2l, w3b, fix_cnt);
    y12_kernel<<<(BC / 32) * (NDIM / 64), 256, 0, stream>>>(s8, w1q, w2h, w2l,
                                                            cnt, z, fix_cnt,
                                                            fix_idx, fix_y1);
    fixup_kernel<<<512, 256, 0, stream>>>(s8, w2, fix_idx, fix_y1, fix_cnt, z);
    out_kernel<<<(TBC / 128) * (NDIM / 128), 256, 0, stream>>>(z, w3b, out);
}